// Round 15
// baseline (1723.297 us; speedup 1.0000x reference)
//
#include <hip/hip_runtime.h>
#include <cstdint>
#include <cstddef>

// ---------------- problem constants (fixed by setup_inputs) ----------------
static constexpr int V3   = 100000;
static constexpr int VM   = 25000;
static constexpr int KE   = 128;
static constexpr int E3   = 800000;
static constexpr int EM   = 200000;
static constexpr int C3   = 128;
static constexpr int CMID = 256;

typedef unsigned short u16;
typedef unsigned int   u32;
using short8v = __attribute__((ext_vector_type(8))) short;
using f32x4   = __attribute__((ext_vector_type(4))) float;
using f32x16  = __attribute__((ext_vector_type(16))) float;

#define DEVI __device__ __forceinline__
DEVI float4 ld4(const float* p){ return *(const float4*)p; }
DEVI void   st4(float* p, float4 v){ *(float4*)p = v; }
DEVI float  bf2f(u16 u){ return __uint_as_float(((u32)u) << 16); }
DEVI u16    f2bf(float f){
  u32 u = __float_as_uint(f);
  u += 0x7FFFu + ((u >> 16) & 1u);   // RNE
  return (u16)(u >> 16);
}
DEVI u32 pk2(float a, float b){ return (u32)f2bf(a) | ((u32)f2bf(b) << 16); }
DEVI short8v as8(uint4 v){ union { uint4 u; short8v s; } c; c.u = v; return c.s; }
// swizzled LDS tile addressing (rows of 32 u16 = 4 octets, stride 40 u16)
DEVI int lofs(int row, int oct){ return row * 40 + ((oct ^ ((row >> 3) & 3)) << 3); }

static inline int cdiv(int a, int b){ return (a + b - 1) / b; }

// ---------------- batched-dispatch descriptor structs ----------------
struct PrepT { const float* W[22]; u16* WT[22]; int K[22]; int N[22]; };
struct CvtT  { const float* src[2]; u16* dst[2]; int n[2]; };
struct IniT  { const u16* src[4]; u16* dst[4]; };
struct GDesc {
  const int* idx; const float* val; const u16* Ebf; u16* GE;
  int* rowptr; int* deg; int* rank; int* excl; int* bsum;
  uint2* epack; int E; int V;   // packed (col, val-bits) per edge
};
struct G4 { GDesc d[4]; };

// =====================================================================
// MFMA GEMM (proven structure): BM=64 rows, BN=128 cols, 4 waves.
// =====================================================================
template<bool RELU, bool RES, bool GATHER, bool OBF16>
__global__ __launch_bounds__(256)
void k_mgemm(const void* __restrict__ A0, int aty0, int K0,
             const u16* __restrict__ wt0, int wl0, int wo0,
             const void* __restrict__ A1, int aty1, int K1,
             const u16* __restrict__ wt1, int wl1, int wo1,
             const void* __restrict__ A2, int aty2, int K2,
             const u16* __restrict__ wt2, int wl2, int wo2,
             const int* __restrict__ gidx,
             const float* __restrict__ bias, const float* __restrict__ res,
             void* __restrict__ OUT, u16* __restrict__ OUTB, int CO, int V)
{
  __shared__ __align__(16) u16 As[64 * 40];
  __shared__ __align__(16) u16 Ws[128 * 40];

  const int tid  = threadIdx.x;
  const int wave = tid >> 6, lane = tid & 63;
  const int vbase = blockIdx.x * 64;
  const int ncol0 = blockIdx.y * 128;
  const int KT = K0 + K1 + K2;

  f32x4 acc[8];
  #pragma unroll
  for (int n = 0; n < 8; n++) { acc[n][0]=0.f; acc[n][1]=0.f; acc[n][2]=0.f; acc[n][3]=0.f; }

  const int ar = tid >> 2, ac = tid & 3;
  const int arow = vbase + ar;
  int grow0 = arow;
  if (GATHER && arow < V) grow0 = gidx[arow];

  for (int kt = 0; kt < KT; kt += 32) {
    { // A stage
      int kg = kt + ac * 8;
      uint4 aw = make_uint4(0,0,0,0);
      if (arow < V && kg < KT) {
        const void* src; int aty, koff, sK; bool s0;
        if (kg < K0)            { src=A0; aty=aty0; koff=0;     sK=K0; s0=true;  }
        else if (kg < K0 + K1)  { src=A1; aty=aty1; koff=K0;    sK=K1; s0=false; }
        else                    { src=A2; aty=aty2; koff=K0+K1; sK=K2; s0=false; }
        int row = (GATHER && s0) ? grow0 : arow;
        int kl = kg - koff;
        if (aty) {
          aw = *(const uint4*)((const u16*)src + (size_t)row * sK + kl);
        } else {
          const float* fp = (const float*)src + (size_t)row * sK + kl;
          float4 x = ld4(fp), y = ld4(fp + 4);
          aw = make_uint4(pk2(x.x,x.y), pk2(x.z,x.w), pk2(y.x,y.y), pk2(y.z,y.w));
        }
      }
      *(uint4*)&As[ar * 40 + ac * 8] = aw;
    }
    #pragma unroll
    for (int i = 0; i < 2; i++) { // W stage
      int col = tid & 127;
      int c = (tid >> 7) + 2 * i;
      int kg = kt + c * 8;
      uint4 ww = make_uint4(0,0,0,0);
      if (kg < KT) {
        const u16* wt; int koff, wl, wo;
        if (kg < K0)           { wt=wt0; koff=0;     wl=wl0; wo=wo0; }
        else if (kg < K0+K1)   { wt=wt1; koff=K0;    wl=wl1; wo=wo1; }
        else                   { wt=wt2; koff=K0+K1; wl=wl2; wo=wo2; }
        ww = *(const uint4*)(wt + (size_t)(ncol0 + col) * wl + wo + (kg - koff));
      }
      *(uint4*)&Ws[col * 40 + c * 8] = ww;
    }
    __syncthreads();
    {
      const int mrow = (wave << 4) + (lane & 15);
      const int kc = lane >> 4;
      short8v a = *(const short8v*)(const void*)&As[mrow * 40 + kc * 8];
      #pragma unroll
      for (int n = 0; n < 8; n++) {
        short8v b = *(const short8v*)(const void*)&Ws[(n * 16 + (lane & 15)) * 40 + kc * 8];
        acc[n] = __builtin_amdgcn_mfma_f32_16x16x32_bf16(a, b, acc[n], 0, 0, 0);
      }
    }
    __syncthreads();
  }

  const int q4 = (lane >> 4) * 4, colb = lane & 15;
  #pragma unroll
  for (int n = 0; n < 8; n++) {
    int gcol = ncol0 + n * 16 + colb;
    float bv = bias ? bias[gcol] : 0.f;
    #pragma unroll
    for (int q = 0; q < 4; q++) {
      int grow = vbase + (wave << 4) + q4 + q;
      if (grow >= V) continue;
      float o = acc[n][q] + bv;
      size_t idx = (size_t)grow * CO + gcol;
      if (RES) o += res[idx];
      if (RELU) o = fmaxf(o, 0.f);
      if (OBF16) ((u16*)OUT)[idx] = f2bf(o);
      else {
        ((float*)OUT)[idx] = o;
        if (OUTB) OUTB[idx] = f2bf(o);
      }
    }
  }
}

// =====================================================================
// Fused C3-block MLP (round-7 proven form) with LDS overlay:
// Hs chunk 0 aliases the As staging buffer (As is dead after phase 1's
// closing barrier; every hwrite->read pair is barrier-ordered).
// LDS: 30720 B -> 5 blocks/CU (was 35840 B -> 4).
// h1=relu([x|gf|E]@w0+b0); h2=relu(h1@w1+b1); out=h2@w2+b2+XM -> XM,SHB
// =====================================================================
__global__ __launch_bounds__(256)
void k_mlp3(const u16* __restrict__ A0, const u16* __restrict__ A1,
            const u16* __restrict__ A2,                     // [V][128] each
            const u16* __restrict__ w0t,                    // [128][384] x|gf|SW
            const u16* __restrict__ w1t, const u16* __restrict__ w2t, // [128][128]
            const float* __restrict__ b0, const float* __restrict__ b1,
            const float* __restrict__ b2,
            float* __restrict__ XM, u16* __restrict__ SHB, int V)
{
  // [0,2560): As / Hs chunk 0   [2560,7680): Ws   [7680,15360): Hs chunks 1-3
  __shared__ __align__(16) u16 SM[15360];
  u16* As = SM;
  u16* Ws = SM + 2560;
  auto hsp = [&](int ch) -> u16* {            // Hs chunk base
    return (ch == 0) ? SM : SM + 7680 + (ch - 1) * 2560;
  };

  const int tid  = threadIdx.x;
  const int wave = tid >> 6, lane = tid & 63;
  const int vbase = blockIdx.x * 64;
  const int ar = tid >> 2, ac = tid & 3;
  const int arow = vbase + ar;
  const bool rok = arow < V;
  const int mrow = (wave << 4) + (lane & 15);
  const int kc = lane >> 4;
  const int q4 = (lane >> 4) * 4, colb = lane & 15;

  f32x4 acc[8];
  auto zacc = [&]{
    #pragma unroll
    for (int n = 0; n < 8; n++) { acc[n][0]=0.f; acc[n][1]=0.f; acc[n][2]=0.f; acc[n][3]=0.f; }
  };
  auto hwrite = [&](const float* b){
    #pragma unroll
    for (int n = 0; n < 8; n++) {
      int c = n * 16 + colb;                  // c>>5 == n>>1 (compile-time)
      float bv = b[c];
      u16* hc = hsp(n >> 1);
      #pragma unroll
      for (int q = 0; q < 4; q++) {
        int row = (wave << 4) + q4 + q;
        hc[lofs(row, (c >> 3) & 3) + (c & 7)] = f2bf(fmaxf(acc[n][q] + bv, 0.f));
      }
    }
  };
  auto mfma_tile = [&](const u16* a8){
    short8v a = *(const short8v*)(const void*)a8;
    #pragma unroll
    for (int n = 0; n < 8; n++) {
      short8v b = *(const short8v*)(const void*)&Ws[(n * 16 + (lane & 15)) * 40 + kc * 8];
      acc[n] = __builtin_amdgcn_mfma_f32_16x16x32_bf16(a, b, acc[n], 0, 0, 0);
    }
  };

  // ---------- phase 1: KT=384 over [A0|A1|A2], weights w0t ----------
  zacc();
  for (int kt = 0; kt < 384; kt += 32) {
    {
      int kg = kt + ac * 8;
      const u16* src = (kg < 128) ? A0 : (kg < 256) ? A1 : A2;
      int kl = kg & 127;
      uint4 aw = make_uint4(0,0,0,0);
      if (rok) aw = *(const uint4*)(src + (size_t)arow * 128 + kl);
      *(uint4*)&As[ar * 40 + ac * 8] = aw;
    }
    #pragma unroll
    for (int i = 0; i < 2; i++) {
      int col = tid & 127, c = (tid >> 7) + 2 * i;
      *(uint4*)&Ws[col * 40 + c * 8] =
        *(const uint4*)(w0t + (size_t)col * 384 + kt + c * 8);
    }
    __syncthreads();
    mfma_tile(&As[mrow * 40 + kc * 8]);
    __syncthreads();                          // drains As reads before hwrite
  }
  hwrite(b0);
  // ---------- phase 2: K=128 over Hs, weights w1t ----------
  zacc();
  for (int kt = 0; kt < 128; kt += 32) {
    #pragma unroll
    for (int i = 0; i < 2; i++) {
      int col = tid & 127, c = (tid >> 7) + 2 * i;
      *(uint4*)&Ws[col * 40 + c * 8] =
        *(const uint4*)(w1t + (size_t)col * 128 + kt + c * 8);
    }
    __syncthreads();   // orders hwrite + Ws stage before reads
    mfma_tile(&hsp(kt >> 5)[lofs(mrow, kc)]);
    __syncthreads();
  }
  hwrite(b1);
  // ---------- phase 3: K=128 over Hs, weights w2t + residual epilogue ----------
  zacc();
  for (int kt = 0; kt < 128; kt += 32) {
    #pragma unroll
    for (int i = 0; i < 2; i++) {
      int col = tid & 127, c = (tid >> 7) + 2 * i;
      *(uint4*)&Ws[col * 40 + c * 8] =
        *(const uint4*)(w2t + (size_t)col * 128 + kt + c * 8);
    }
    __syncthreads();
    mfma_tile(&hsp(kt >> 5)[lofs(mrow, kc)]);
    __syncthreads();
  }
  #pragma unroll
  for (int n = 0; n < 8; n++) {
    int gcol = n * 16 + colb;
    float bv = b2[gcol];
    #pragma unroll
    for (int q = 0; q < 4; q++) {
      int grow = vbase + (wave << 4) + q4 + q;
      if (grow >= V) continue;
      size_t idx = (size_t)grow * C3 + gcol;
      float o = acc[n][q] + bv + XM[idx];
      XM[idx] = o;
      SHB[idx] = f2bf(o);
    }
  }
}

// =====================================================================
// Register-resident MFMA megagate (no LDS, no barriers).
// =====================================================================
__global__ __launch_bounds__(256)
void k_mgate_reg(const u16* __restrict__ GEX, const u16* __restrict__ GEY,
                 const u16* __restrict__ pS, const u16* __restrict__ pR,
                 const u16* __restrict__ pI,
                 u16* __restrict__ GF, int CO, int V)
{
  const int lane = threadIdx.x & 63;
  const int wave = threadIdx.x >> 6;
  const int rbase = blockIdx.x * 128 + wave * 32;
  const int arow = rbase + (lane & 31);
  const int koff = (lane >> 5) * 8;
  const bool rok = arow < V;

  uint4 ax[8], ay[8], an[8];
  #pragma unroll
  for (int kt = 0; kt < 8; kt++) {
    uint4 zx = make_uint4(0,0,0,0), zy = make_uint4(0,0,0,0);
    if (rok) {
      zx = *(const uint4*)(GEX + (size_t)arow * KE + kt * 16 + koff);
      zy = *(const uint4*)(GEY + (size_t)arow * KE + kt * 16 + koff);
    }
    ax[kt] = zx; ay[kt] = zy;
    an[kt] = make_uint4(zy.x ^ 0x80008000u, zy.y ^ 0x80008000u,
                        zy.z ^ 0x80008000u, zy.w ^ 0x80008000u);
  }

  const int ngr = CO >> 5;
  for (int g = 0; g < ngr; g++) {
    f32x16 gx, gy, br, bi;
    #pragma unroll
    for (int r = 0; r < 16; r++) { gx[r]=0.f; gy[r]=0.f; br[r]=0.f; bi[r]=0.f; }
    #pragma unroll
    for (int kt = 0; kt < 8; kt++) {
      size_t bo = ((size_t)(g * 8 + kt) * 64 + lane) * 8;
      short8v bs  = *(const short8v*)(const void*)(pS + bo);
      short8v brv = *(const short8v*)(const void*)(pR + bo);
      short8v biv = *(const short8v*)(const void*)(pI + bo);
      short8v axv = as8(ax[kt]), ayv = as8(ay[kt]), anv = as8(an[kt]);
      gx = __builtin_amdgcn_mfma_f32_32x32x16_bf16(axv, bs,  gx, 0, 0, 0);
      gy = __builtin_amdgcn_mfma_f32_32x32x16_bf16(ayv, bs,  gy, 0, 0, 0);
      br = __builtin_amdgcn_mfma_f32_32x32x16_bf16(axv, brv, br, 0, 0, 0);
      br = __builtin_amdgcn_mfma_f32_32x32x16_bf16(anv, biv, br, 0, 0, 0);
      bi = __builtin_amdgcn_mfma_f32_32x32x16_bf16(axv, biv, bi, 0, 0, 0);
      bi = __builtin_amdgcn_mfma_f32_32x32x16_bf16(ayv, brv, bi, 0, 0, 0);
    }
    const int col = g * 32 + (lane & 31);
    const int rhi = 4 * (lane >> 5);
    #pragma unroll
    for (int r = 0; r < 16; r++) {
      int row = rbase + (r & 3) + 8 * (r >> 2) + rhi;
      if (row < V) {
        float o = tanhf(gx[r] * br[r] + gy[r] * bi[r]);
        GF[(size_t)row * CO + col] = f2bf(o);
      }
    }
  }
}

// =====================================================================
// MFMA spectral down-projection (bf16 inputs), split-K + f32 atomics.
// =====================================================================
__global__ __launch_bounds__(256)
void k_specmm(const u16* __restrict__ E, const u16* __restrict__ X,
              const float* __restrict__ mass, float* __restrict__ SPEC,
              int C, int V, int CH)
{
  __shared__ __align__(16) u16 As[64 * 40];
  __shared__ __align__(16) u16 Bs[128 * 40];

  const int tid = threadIdx.x;
  const int wave = tid >> 6, lane = tid & 63;
  const int m0 = blockIdx.y * 64;
  const int n0 = blockIdx.z * 128;
  const int vs = blockIdx.x * CH;
  const int ve = min(V, vs + CH);

  f32x4 acc[8];
  #pragma unroll
  for (int n = 0; n < 8; n++) { acc[n][0]=0.f; acc[n][1]=0.f; acc[n][2]=0.f; acc[n][3]=0.f; }

  const int am = tid & 63, ac = tid >> 6;
  const int bcol = tid & 127, bc0 = (tid >> 7) * 2;

  u16 ea[8]; float fb0[8], fb1[8], fm0[8], fm1[8];
  auto loadA = [&](int kt) {
    #pragma unroll
    for (int j = 0; j < 8; j++) {
      int v = kt + ac * 8 + j;
      ea[j] = (v < ve) ? E[(size_t)v * KE + m0 + am] : (u16)0;
    }
  };
  auto loadB = [&](int kt) {
    #pragma unroll
    for (int j = 0; j < 8; j++) {
      int v0 = kt + bc0 * 8 + j, v1 = v0 + 8;
      fb0[j] = (v0 < ve) ? bf2f(X[(size_t)v0 * C + n0 + bcol]) : 0.f;
      fm0[j] = (v0 < ve) ? mass[v0] : 0.f;
      fb1[j] = (v1 < ve) ? bf2f(X[(size_t)v1 * C + n0 + bcol]) : 0.f;
      fm1[j] = (v1 < ve) ? mass[v1] : 0.f;
    }
  };
  loadA(vs); loadB(vs);

  for (int kt = vs; kt < ve; kt += 32) {
    __syncthreads();
    *(uint4*)&As[lofs(am, ac)] = make_uint4(
        (u32)ea[0] | ((u32)ea[1] << 16), (u32)ea[2] | ((u32)ea[3] << 16),
        (u32)ea[4] | ((u32)ea[5] << 16), (u32)ea[6] | ((u32)ea[7] << 16));
    float t0[8], t1[8];
    #pragma unroll
    for (int j = 0; j < 8; j++) { t0[j] = fb0[j]*fm0[j]; t1[j] = fb1[j]*fm1[j]; }
    *(uint4*)&Bs[lofs(bcol, bc0)] = make_uint4(
        pk2(t0[0],t0[1]), pk2(t0[2],t0[3]), pk2(t0[4],t0[5]), pk2(t0[6],t0[7]));
    *(uint4*)&Bs[lofs(bcol, bc0 + 1)] = make_uint4(
        pk2(t1[0],t1[1]), pk2(t1[2],t1[3]), pk2(t1[4],t1[5]), pk2(t1[6],t1[7]));
    __syncthreads();
    if (kt + 32 < ve) { loadA(kt + 32); loadB(kt + 32); }
    const int kc = lane >> 4, ml = lane & 15;
    short8v a = *(const short8v*)(const void*)&As[lofs(wave * 16 + ml, kc)];
    #pragma unroll
    for (int n = 0; n < 8; n++) {
      short8v b = *(const short8v*)(const void*)&Bs[lofs(n * 16 + ml, kc)];
      acc[n] = __builtin_amdgcn_mfma_f32_16x16x32_bf16(a, b, acc[n], 0, 0, 0);
    }
  }

  const int q4 = (lane >> 4) * 4, colb = lane & 15;
  #pragma unroll
  for (int n = 0; n < 8; n++) {
    int col = n0 + n * 16 + colb;
    #pragma unroll
    for (int q = 0; q < 4; q++) {
      int row = m0 + wave * 16 + q4 + q;
      unsafeAtomicAdd(&SPEC[(size_t)row * C + col], acc[n][q]);
    }
  }
}

// =====================================================================
// smallprep: packed B-fragment S/Tr/Ti + flat SWt; zeroes SPEC after
// reading. If wcmb != null also writes SW into wCmb slot.
// =====================================================================
template<int C>
__global__ void k_smallprep(float* __restrict__ SPEC, const float* __restrict__ evals,
                            const float* __restrict__ dt, const float* __restrict__ Are,
                            const float* __restrict__ Aim, const float* __restrict__ w0,
                            u16* __restrict__ pS, u16* __restrict__ pR,
                            u16* __restrict__ pI, u16* __restrict__ SWt,
                            u16* __restrict__ wcmb)
{
  __shared__ float sld[C];
  const int k = blockIdx.x;
  const int c = threadIdx.x;
  const float ev = evals[k];
  float s = expf(-ev * fmaxf(dt[c], 1e-8f)) * SPEC[(size_t)k * C + c];
  SPEC[(size_t)k * C + c] = 0.f;   // re-zero for the next block's atomics
  sld[c] = s;
  const size_t pidx = ((size_t)((c >> 5) * 8 + (k >> 4)) * 64
                       + (c & 31) + ((k >> 3) & 1) * 32) * 8 + (k & 7);
  pS[pidx] = f2bf(s);
  __syncthreads();
  float tr = 0.f, ti = 0.f, sw = 0.f;
  for (int j = 0; j < C; j++) {
    float sj = sld[j];
    tr = fmaf(sj, Are[(size_t)j * C + c], tr);
    ti = fmaf(sj, Aim[(size_t)j * C + c], ti);
    sw = fmaf(sj, w0[(size_t)(C + j) * C + c], sw);
  }
  pR[pidx] = f2bf(tr);
  pI[pidx] = f2bf(ti);
  u16 swb = f2bf(sw);
  SWt[(size_t)c * 128 + k] = swb;
  if (wcmb) wcmb[(size_t)c * 384 + 256 + k] = swb;
}

// ===== batched weight pre-transpose: 22 entries, grid (768, 22) =====
__global__ void k_prepw_b(PrepT p) {
  int e = blockIdx.y;
  int i = blockIdx.x * 256 + threadIdx.x;
  int K = p.K[e], N = p.N[e];
  if (i < K * N) {
    int k = i / N, n = i % N;
    p.WT[e][(size_t)n * K + k] = f2bf(p.W[e][i]);
  }
}

// ===== batched f32->bf16 cvt: 2 entries =====
__global__ void k_cvt_b(CvtT c) {
  int e = blockIdx.y;
  int i = (blockIdx.x * 256 + threadIdx.x) * 4;
  if (i < c.n[e]) {
    float4 v = ld4(c.src[e] + i);
    ushort4 o; o.x = f2bf(v.x); o.y = f2bf(v.y); o.z = f2bf(v.z); o.w = f2bf(v.w);
    *(ushort4*)(c.dst[e] + i) = o;
  }
}

// ===== init 4 wCmb static parts: [col][0:128]=x, [128:256]=gf =====
__global__ void k_initwc(IniT t) {
  int e = blockIdx.y;
  int i = blockIdx.x * 256 + threadIdx.x;   // 32768 elements
  int col = i >> 8, k = i & 255;
  t.dst[e][(size_t)col * 384 + k] =
      (k < 128) ? t.src[e][(size_t)col * 384 + k]
                : t.src[e][(size_t)col * 384 + 128 + k];
}

// ===== f32 -> bf16 single (decoder rebuild) =====
__global__ void k_cvt(const float* __restrict__ in, u16* __restrict__ out, int n) {
  int i = (blockIdx.x * 256 + threadIdx.x) * 4;
  if (i < n) {
    float4 v = ld4(in + i);
    ushort4 o; o.x = f2bf(v.x); o.y = f2bf(v.y); o.z = f2bf(v.z); o.w = f2bf(v.w);
    *(ushort4*)(out + i) = o;
  }
}

// ==================== batched 4-graph CSR build ======================
// hist ALSO captures each edge's within-row rank (the atomic's return
// value) so the scatter pass needs NO atomic at all.
__global__ void k_bhist(G4 g) {
  const GDesc& d = g.d[blockIdx.y];
  int e = blockIdx.x * 256 + threadIdx.x;
  if (e < d.E) d.rank[e] = atomicAdd(&d.deg[d.idx[2 * e]], 1);
}
__global__ void k_bscan1(G4 g) {
  const GDesc& d = g.d[blockIdx.y];
  __shared__ int sd[256];
  int t = threadIdx.x;
  int i = blockIdx.x * 256 + t;
  int v = (i < d.V) ? d.deg[i] : 0;
  sd[t] = v;
  __syncthreads();
  for (int off = 1; off < 256; off <<= 1) {
    int add = (t >= off) ? sd[t - off] : 0;
    __syncthreads();
    sd[t] += add;
    __syncthreads();
  }
  if (i < d.V) d.excl[i] = sd[t] - v;
  if (t == 255) d.bsum[blockIdx.x] = sd[255];
}
__global__ void k_bscan2(G4 g, int nb) {
  const GDesc& d = g.d[blockIdx.y];
  __shared__ int sd[512];
  int t = threadIdx.x;
  int v = (t < nb) ? d.bsum[t] : 0;
  sd[t] = v;
  __syncthreads();
  for (int off = 1; off < 512; off <<= 1) {
    int add = (t >= off) ? sd[t - off] : 0;
    __syncthreads();
    sd[t] += add;
    __syncthreads();
  }
  if (t < nb) d.bsum[t] = sd[t] - v;
  if (t == 0) d.rowptr[d.V] = sd[511];
}
__global__ void k_bscan3(G4 g) {
  const GDesc& d = g.d[blockIdx.y];
  int i = blockIdx.x * 256 + threadIdx.x;
  if (i < d.V) d.rowptr[i] = d.excl[i] + d.bsum[i >> 8];
}
// atomic-free packed scatter: ONE 8B store per edge.
__global__ void k_bscatter(G4 g) {
  const GDesc& d = g.d[blockIdx.y];
  int e = blockIdx.x * 256 + threadIdx.x;
  if (e < d.E) {
    int dd = d.idx[2 * e];
    int p = d.rowptr[dd] + d.rank[e];
    d.epack[p] = make_uint2((u32)d.idx[2 * e + 1], __float_as_uint(d.val[e]));
  }
}
// 4-way edge-unrolled gather spmm over packed edges (4 gathers in flight).
__global__ __launch_bounds__(256)
void k_bspmm(G4 g) {
  const GDesc& d = g.d[blockIdx.y];
  int r = blockIdx.x * 8 + (threadIdx.x >> 5);
  int lane = threadIdx.x & 31;
  if (r >= d.V) return;
  int j0 = d.rowptr[r], j1 = d.rowptr[r + 1];
  float4 a0 = make_float4(0.f,0.f,0.f,0.f);
  float4 a1 = make_float4(0.f,0.f,0.f,0.f);
  float4 a2 = make_float4(0.f,0.f,0.f,0.f);
  float4 a3 = make_float4(0.f,0.f,0.f,0.f);
  int j = j0;
  for (; j + 4 <= j1; j += 4) {
    uint2 e0 = d.epack[j],     e1 = d.epack[j + 1];
    uint2 e2 = d.epack[j + 2], e3 = d.epack[j + 3];
    float v0 = __uint_as_float(e0.y), v1 = __uint_as_float(e1.y);
    float v2 = __uint_as_float(e2.y), v3 = __uint_as_float(e3.y);
    ushort4 x0 = *(const ushort4*)(d.Ebf + (size_t)e0.x * KE + lane * 4);
    ushort4 x1 = *(const ushort4*)(d.Ebf + (size_t)e1.x * KE + lane * 4);
    ushort4 x2 = *(const ushort4*)(d.Ebf + (size_t)e2.x * KE + lane * 4);
    ushort4 x3 = *(const ushort4*)(d.Ebf + (size_t)e3.x * KE + lane * 4);
    a0.x = fmaf(v0, bf2f(x0.x), a0.x); a0.y = fmaf(v0, bf2f(x0.y), a0.y);
    a0.z = fmaf(v0, bf2f(x0.z), a0.z); a0.w = fmaf(v0, bf2f(x0.w), a0.w);
    a1.x = fmaf(v1, bf2f(x1.x), a1.x); a1.y = fmaf(v1, bf2f(x1.y), a1.y);
    a1.z = fmaf(v1, bf2f(x1.z), a1.z); a1.w = fmaf(v1, bf2f(x1.w), a1.w);
    a2.x = fmaf(v2, bf2f(x2.x), a2.x); a2.y = fmaf(v2, bf2f(x2.y), a2.y);
    a2.z = fmaf(v2, bf2f(x2.z), a2.z); a2.w = fmaf(v2, bf2f(x2.w), a2.w);
    a3.x = fmaf(v3, bf2f(x3.x), a3.x); a3.y = fmaf(v3, bf2f(x3.y), a3.y);
    a3.z = fmaf(v3, bf2f(x3.z), a3.z); a3.w = fmaf(v3, bf2f(x3.w), a3.w);
  }
  if (j + 2 <= j1) {
    uint2 e0 = d.epack[j], e1 = d.epack[j + 1];
    float v0 = __uint_as_float(e0.y), v1 = __uint_as_float(e1.y);
    ushort4 x0 = *(const ushort4*)(d.Ebf + (size_t)e0.x * KE + lane * 4);
    ushort4 x1 = *(const ushort4*)(d.Ebf + (size_t)e1.x * KE + lane * 4);
    a0.x = fmaf(v0, bf2f(x0.x), a0.x); a0.y = fmaf(v0, bf2f(x0.y), a0.y);
    a0.z = fmaf(v0, bf2f(x0.z), a0.z); a0.w = fmaf(v0, bf2f(x0.w), a0.w);
    a1.x = fmaf(v1, bf2f(x1.x), a1.x); a1.y = fmaf(v1, bf2f(x1.y), a1.y);
    a1.z = fmaf(v1, bf2f(x1.z), a1.z); a1.w = fmaf(v1, bf2f(x1.w), a1.w);
    j += 2;
  }
  if (j < j1) {
    uint2 e0 = d.epack[j];
    float v0 = __uint_as_float(e0.y);
    ushort4 x0 = *(const ushort4*)(d.Ebf + (size_t)e0.x * KE + lane * 4);
    a0.x = fmaf(v0, bf2f(x0.x), a0.x); a0.y = fmaf(v0, bf2f(x0.y), a0.y);
    a0.z = fmaf(v0, bf2f(x0.z), a0.z); a0.w = fmaf(v0, bf2f(x0.w), a0.w);
  }
  a0.x += a1.x + a2.x + a3.x;
  a0.y += a1.y + a2.y + a3.y;
  a0.z += a1.z + a2.z + a3.z;
  a0.w += a1.w + a2.w + a3.w;
  ushort4 o;
  o.x = f2bf(a0.x); o.y = f2bf(a0.y); o.z = f2bf(a0.z); o.w = f2bf(a0.w);
  *(ushort4*)(d.GE + (size_t)r * KE + lane * 4) = o;
}

// ============================ segment max ============================
__global__ void k_segmax_init(unsigned* __restrict__ u, int n) {
  int i = blockIdx.x * 256 + threadIdx.x;
  if (i < n) u[i] = 0x007FFFFFu;
}
__global__ void k_segmax_scatter(const u16* __restrict__ X, const int* __restrict__ tr,
                                 unsigned* __restrict__ u) {
  int i = blockIdx.x * 256 + threadIdx.x;
  if (i >= V3 * C3) return;
  int v = i >> 7, c = i & 127;
  unsigned b = ((unsigned)X[i]) << 16;
  unsigned m = (b & 0x80000000u) ? ~b : (b | 0x80000000u);
  atomicMax(&u[((size_t)tr[v] << 7) + c], m);
}
__global__ void k_segmax_decode(const unsigned* __restrict__ u, u16* __restrict__ out, int n) {
  int i = blockIdx.x * 256 + threadIdx.x;
  if (i < n) {
    unsigned m = u[i];
    unsigned b = 0;
    if (m != 0x007FFFFFu)
      b = (m & 0x80000000u) ? (m & 0x7FFFFFFFu) : ~m;
    out[i] = (u16)(b >> 16);
  }
}

// ========================= final projection ==========================
__global__ __launch_bounds__(256)
void k_outproj(const float* __restrict__ Y, const float* __restrict__ W,
               const float* __restrict__ B, float* __restrict__ OUT, int V) {
  __shared__ float Wl[128][22];
  __shared__ float ys[8][128];
  const int tid = threadIdx.x;
  for (int f = tid; f < 128 * 21; f += 256) Wl[f / 21][f % 21] = W[f];
  {
    int r = tid >> 5, cc = (tid & 31) * 4;
    int v = blockIdx.x * 8 + r;
    float4 yv = make_float4(0.f,0.f,0.f,0.f);
    if (v < V) yv = ld4(Y + (size_t)v * C3 + cc);
    st4(&ys[r][cc], yv);
  }
  __syncthreads();
  int r = tid >> 5, c = tid & 31;
  int v = blockIdx.x * 8 + r;
  if (v < V && c < 21) {
    float acc = B[c];
    #pragma unroll 8
    for (int k = 0; k < 128; k++) acc = fmaf(ys[r][k], Wl[k][c], acc);
    OUT[(size_t)v * 21 + c] = acc;
  }
}

// =====================================================================
extern "C" void kernel_launch(void* const* d_in, const int* in_sizes, int n_in,
                              void* d_out, int out_size, void* d_ws, size_t ws_size,
                              hipStream_t stream)
{
  (void)in_sizes; (void)n_in; (void)out_size;
  const float* x_in    = (const float*)d_in[0];
  const float* mass3   = (const float*)d_in[1];
  const float* evals3  = (const float*)d_in[2];
  const float* evecs3  = (const float*)d_in[3];
  const int*   gX3i    = (const int*)d_in[4];
  const float* gX3v    = (const float*)d_in[5];
  const int*   gY3i    = (const int*)d_in[6];
  const float* gY3v    = (const float*)d_in[7];
  const float* massm   = (const float*)d_in[8];
  const float* evalsm  = (const float*)d_in[9];
  const float* evecsm  = (const float*)d_in[10];
  const int*   gXmi    = (const int*)d_in[11];
  const float* gXmv    = (const float*)d_in[12];
  const int*   gYmi    = (const int*)d_in[13];
  const float* gYmv    = (const float*)d_in[14];
  const int*   tr34    = (const int*)d_in[15];
  const float* in_w    = (const float*)d_in[16];
  const float* in_b    = (const float*)d_in[17];
  const float* widen_w = (const float*)d_in[18];
  const float* widen_b = (const float*)d_in[19];
  const float* narrow_w= (const float*)d_in[20];
  const float* narrow_b= (const float*)d_in[21];
  const float* halve_w = (const float*)d_in[22];
  const float* halve_b = (const float*)d_in[23];
  const float* out_w   = (const float*)d_in[24];
  const float* out_b   = (const float*)d_in[25];
  const float* enc_p[9]; const float* mid_p[9]; const float* dec_p[9];
  for (int i = 0; i < 9; i++) {
    enc_p[i] = (const float*)d_in[26 + i];
    mid_p[i] = (const float*)d_in[35 + i];
    dec_p[i] = (const float*)d_in[44 + i];
  }

  // ---------------- workspace layout (~214 MB) ----------------
  char* ws = (char*)d_ws;
  size_t off = 0;
  float* XM  = (float*)(ws + off); off += (size_t)V3 * C3 * 4;
  u16* SHB   = (u16*)(ws + off);   off += (size_t)V3 * C3 * 2;
  u16* GEX3  = (u16*)(ws + off);   off += (size_t)V3 * KE * 2;
  u16* GEY3  = (u16*)(ws + off);   off += (size_t)V3 * KE * 2;
  u16* GEXm  = (u16*)(ws + off);   off += (size_t)VM * KE * 2;
  u16* GEYm  = (u16*)(ws + off);   off += (size_t)VM * KE * 2;
  u16* BSCR  = (u16*)(ws + off);   off += (size_t)V3 * C3 * 2;
  char* E3R  = (char*)(ws + off);  off += (size_t)V3 * KE * 2;
  u16* Embf  = (u16*)(ws + off);   off += (size_t)VM * KE * 2;
  u16* SHM   = (u16*)(ws + off);   off += (size_t)VM * CMID * 2;
  float* spec= (float*)(ws + off); off += 131072;
  u16* pS  = (u16*)(ws + off); off += 65536;
  u16* pR  = (u16*)(ws + off); off += 65536;
  u16* pI  = (u16*)(ws + off); off += 65536;
  u16* SWt = (u16*)(ws + off); off += 65536;
  u16* wT  = (u16*)(ws + off); off += 2800000;
  const size_t NEED = off;
  if (ws_size < NEED) return;

  u16*   E3bf = (u16*)E3R;
  float* M0   = (float*)E3R;
  // pool overlays BSCR (dead at pool time)
  unsigned* xm_u  = (unsigned*)BSCR;
  u16*      xm_dec= (u16*)((char*)BSCR + 12800000);
  u16* BSCR0 = BSCR;
  u16* BSCR1 = BSCR + (size_t)VM * CMID;

  u16* in_wt    = wT + 0;
  u16* widen_t  = wT + 2048;
  u16* narrow_t = wT + 34816;
  u16* halve_t  = wT + 67584;
  u16* enc_w0t  = wT + 100352;
  u16* enc_w1t  = wT + 198656;
  u16* enc_w2t  = wT + 231424;
  u16* mid_w0t  = wT + 264192;
  u16* mid_w1t  = wT + 657408;
  u16* mid_w2t  = wT + 788480;
  u16* dec_w0t  = wT + 919552;
  u16* dec_w1t  = wT + 1017856;
  u16* dec_w2t  = wT + 1050624;
  u16* wCmb[4]  = { wT + 1083392, wT + 1181696, wT + 1280000, wT + 1378304 };

  // ---- batched weight pre-transpose (1 dispatch) ----
  {
    PrepT p;
    int e = 0;
    auto add = [&](const float* W, u16* WT, int K, int N, int z) {
      for (int i = 0; i < z; i++) {
        p.W[e] = W + (size_t)i * K * N; p.WT[e] = WT + (size_t)i * K * N;
        p.K[e] = K; p.N[e] = N; e++;
      }
    };
    add(in_w, in_wt, 16, 128, 1);
    add(widen_w, widen_t, 128, 256, 1);
    add(narrow_w, narrow_t, 256, 128, 1);
    add(halve_w, halve_t, 256, 128, 1);
    add(enc_p[3], enc_w0t, 384, 128, 2);
    add(enc_p[5], enc_w1t, 128, 128, 2);
    add(enc_p[7], enc_w2t, 128, 128, 2);
    add(mid_p[3], mid_w0t, 768, 256, 2);
    add(mid_p[5], mid_w1t, 256, 256, 2);
    add(mid_p[7], mid_w2t, 256, 256, 2);
    add(dec_p[3], dec_w0t, 384, 128, 2);
    add(dec_p[5], dec_w1t, 128, 128, 2);
    add(dec_p[7], dec_w2t, 128, 128, 2);
    k_prepw_b<<<dim3(768, 22), 256, 0, stream>>>(p);
  }
  // ---- init static parts of the 4 combined-w0 buffers (1 dispatch) ----
  {
    IniT t;
    t.src[0] = enc_w0t; t.dst[0] = wCmb[0];
    t.src[1] = enc_w0t + 49152; t.dst[1] = wCmb[1];
    t.src[2] = dec_w0t; t.dst[2] = wCmb[2];
    t.src[3] = dec_w0t + 49152; t.dst[3] = wCmb[3];
    k_initwc<<<dim3(128, 4), 256, 0, stream>>>(t);
  }
  // ---- evecs -> bf16 (1 dispatch) ----
  {
    CvtT c;
    c.src[0] = evecs3; c.dst[0] = E3bf; c.n[0] = V3 * KE;
    c.src[1] = evecsm; c.dst[1] = Embf; c.n[1] = VM * KE;
    k_cvt_b<<<dim3(cdiv(V3 * KE / 4, 256), 2), 256, 0, stream>>>(c);
  }
  // ---- zero spec ONCE (smallprep re-zeros after each read) ----
  hipMemsetAsync(spec, 0, (size_t)KE * CMID * 4, stream);

  // ---- batched 4-graph CSR build + spmm (7 dispatches) ----
  {
    int* degs = (int*)BSCR;          // 250000 ints
    int* pos  = degs + 250000;
    // rank arrays live in GEX3 (dead until bspmm writes it, which is
    // strictly after bscatter consumes rank)
    int* rankbase = (int*)GEX3;      // 2E3+2EM ints = 8 MB <= 25.6 MB
    G4 g;
    const int*   idxs[4] = { gX3i, gY3i, gXmi, gYmi };
    const float* vals[4] = { gX3v, gY3v, gXmv, gYmv };
    const u16*   ebfs[4] = { E3bf, E3bf, Embf, Embf };
    u16*         ges[4]  = { GEX3, GEY3, GEXm, GEYm };
    int Es[4] = { E3, E3, EM, EM };
    int Vs[4] = { V3, V3, VM, VM };
    int doff[4] = { 0, 100000, 200000, 225000 };
    int roff[4] = { 0, E3, 2 * E3, 2 * E3 + EM };
    for (int i = 0; i < 4; i++) {
      GDesc& d = g.d[i];
      d.idx = idxs[i]; d.val = vals[i]; d.Ebf = ebfs[i]; d.GE = ges[i];
      d.E = Es[i]; d.V = Vs[i];
      d.deg = degs + doff[i];
      d.rank = rankbase + roff[i];
      d.rowptr = pos; pos += Vs[i] + 1;
      d.excl   = pos; pos += Vs[i];
      d.bsum   = pos; pos += 512;
      if (((uintptr_t)pos) & 7) pos++;          // 8B-align packed edges
      d.epack  = (uint2*)pos; pos += 2 * Es[i];
    }
    hipMemsetAsync(degs, 0, 250000 * 4, stream);
    k_bhist<<<dim3(cdiv(E3, 256), 4), 256, 0, stream>>>(g);
    k_bscan1<<<dim3(cdiv(V3, 256), 4), 256, 0, stream>>>(g);
    k_bscan2<<<dim3(1, 4), 512, 0, stream>>>(g, cdiv(V3, 256));
    k_bscan3<<<dim3(cdiv(V3, 256), 4), 256, 0, stream>>>(g);
    k_bscatter<<<dim3(cdiv(E3, 256), 4), 256, 0, stream>>>(g);
    k_bspmm<<<dim3(cdiv(V3, 8), 4), 256, 0, stream>>>(g);
  }

  const int G3 = cdiv(V3, 64);   // 1563
  const int GM = cdiv(VM, 64);   // 391

  // ---- block3: 4 dispatches per block (no memset) ----
  auto launch_block3 = [&](const float* p[9],
                           const u16* w1t, const u16* w2t, u16* wc, int i) {
    const float* dt  = p[0] + (size_t)i * C3;
    const float* Are = p[1] + (size_t)i * C3 * C3;
    const float* Aim = p[2] + (size_t)i * C3 * C3;
    const float* w0  = p[3] + (size_t)i * 3 * C3 * C3;
    const float* b0  = p[4] + (size_t)i * C3;
    const float* b1  = p[6] + (size_t)i * C3;
    const float* b2  = p[8] + (size_t)i * C3;
    const u16* w1ti = w1t + (size_t)i * C3 * C3;
    const u16* w2ti = w2t + (size_t)i * C3 * C3;
    k_specmm<<<dim3(cdiv(V3, 256), 2, 1), 256, 0, stream>>>(E3bf, SHB, mass3, spec, C3, V3, 256);
    k_smallprep<C3><<<KE, C3, 0, stream>>>(spec, evals3, dt, Are, Aim, w0, pS, pR, pI, SWt, wc);
    k_mgate_reg<<<cdiv(V3, 128), 256, 0, stream>>>(GEX3, GEY3, pS, pR, pI, BSCR, C3, V3);
    k_mlp3<<<G3, 256, 0, stream>>>(SHB, BSCR, E3bf, wc, w1ti, w2ti,
                                   b0, b1, b2, XM, SHB, V3);
  };

  // ---- blockm: split (proven), no memset ----
  auto run_blockm = [&](const float* p[9],
                        const u16* w0t, const u16* w1t, const u16* w2t, int i) {
    const float* dt  = p[0] + (size_t)i * CMID;
    const float* Are = p[1] + (size_t)i * CMID * CMID;
    const float* Aim = p[2] + (size_t)i * CMID * CMID;
    const float* w0  = p[3] + (size_t)i * 3 * CMID * CMID;
    const float* b0  = p[4] + (size_t)i * CMID;
    const float* b1  = p[6] + (size_t)i * CMID;
    const float* b2  = p[8] + (size_t)i * CMID;
    const u16* w0ti = w0t + (size_t)i * 3 * CMID * CMID;
    const u16* w1ti = w1t + (size_t)i * CMID * CMID;
    const u16* w2ti = w2t + (size_t)i * CMID * CMID;
    k_specmm<<<dim3(cdiv(VM, 128), 2, 2), 256, 0, stream>>>(Embf, SHM, massm, spec, CMID, VM, 128);
    k_smallprep<CMID><<<KE, CMID, 0, stream>>>(spec, evalsm, dt, Are, Aim, w0, pS, pR, pI, SWt, nullptr);
    k_mgate_reg<<<cdiv(VM, 128), 256, 0, stream>>>(GEXm, GEYm, pS, pR, pI, BSCR0, CMID, VM);
    k_mgemm<true,false,false,true><<<dim3(GM, 2), 256, 0, stream>>>(
        SHM, 1, CMID, w0ti, 3*CMID, 0,
        BSCR0, 1, CMID, w0ti, 3*CMID, 2*CMID,
        Embf, 1, KE, SWt, 128, 0,
        nullptr, b0, nullptr, BSCR1, nullptr, CMID, VM);
    k_mgemm<true,false,false,true><<<dim3(GM, 2), 256, 0, stream>>>(
        BSCR1, 1, CMID, w1ti, CMID, 0,
        nullptr,0,0,nullptr,0,0, nullptr,0,0,nullptr,0,0,
        nullptr, b1, nullptr, BSCR0, nullptr, CMID, VM);
    k_mgemm<false,true,false,false><<<dim3(GM, 2), 256, 0, stream>>>(
        BSCR0, 1, CMID, w2ti, CMID, 0,
        nullptr,0,0,nullptr,0,0, nullptr,0,0,nullptr,0,0,
        nullptr, b2, M0, M0, SHM, CMID, VM);
  };

  // ---- encoder ----
  k_mgemm<true,false,false,false><<<dim3(G3, 1), 256, 0, stream>>>(
      x_in, 0, 16, in_wt, 16, 0,
      nullptr,0,0,nullptr,0,0, nullptr,0,0,nullptr,0,0,
      nullptr, in_b, nullptr, XM, SHB, C3, V3);
  launch_block3(enc_p, enc_w1t, enc_w2t, wCmb[0], 0);
  launch_block3(enc_p, enc_w1t, enc_w2t, wCmb[1], 1);        // x3 = XM/SHB

  // ---- pool (reads bf16 shadow; identical by monotonicity) ----
  k_segmax_init<<<cdiv(VM * C3, 256), 256, 0, stream>>>(xm_u, VM * C3);
  k_segmax_scatter<<<cdiv(V3 * C3, 256), 256, 0, stream>>>(SHB, tr34, xm_u);
  k_segmax_decode<<<cdiv(VM * C3, 256), 256, 0, stream>>>(xm_u, xm_dec, VM * C3);
  k_mgemm<true,false,false,false><<<dim3(GM, 2), 256, 0, stream>>>(
      xm_dec, 1, C3, widen_t, C3, 0,
      nullptr,0,0,nullptr,0,0, nullptr,0,0,nullptr,0,0,
      nullptr, widen_b, nullptr, M0, SHM, CMID, VM);
  run_blockm(mid_p, mid_w0t, mid_w1t, mid_w2t, 0);
  run_blockm(mid_p, mid_w0t, mid_w1t, mid_w2t, 1);           // shadow = SHM

  // ---- unpool ----
  k_mgemm<true,false,true,true><<<dim3(G3, 1), 256, 0, stream>>>(
      SHM, 1, CMID, narrow_t, CMID, 0,
      nullptr,0,0,nullptr,0,0, nullptr,0,0,nullptr,0,0,
      tr34, narrow_b, nullptr, BSCR, nullptr, C3, V3);
  k_mgemm<true,false,false,false><<<dim3(G3, 1), 256, 0, stream>>>(
      BSCR, 1, C3, halve_t, 2*C3, 0,
      SHB, 1, C3, halve_t, 2*C3, C3,
      nullptr,0,0,nullptr,0,0,
      nullptr, halve_b, nullptr, XM, SHB, C3, V3);

  // ---- decoder (rebuild E3bf: clobbered by M0 overlay) ----
  k_cvt<<<cdiv(V3 * KE / 4, 256), 256, 0, stream>>>(evecs3, E3bf, V3 * KE);
  launch_block3(dec_p, dec_w1t, dec_w2t, wCmb[2], 0);
  launch_block3(dec_p, dec_w1t, dec_w2t, wCmb[3], 1);

  // ---- output projection ----
  k_outproj<<<cdiv(V3, 8), 256, 0, stream>>>(XM, out_w, out_b, (float*)d_out, V3);
}

// Round 16
// 1703.004 us; speedup vs baseline: 1.0119x; 1.0119x over previous
//
#include <hip/hip_runtime.h>
#include <cstdint>
#include <cstddef>

// ---------------- problem constants (fixed by setup_inputs) ----------------
static constexpr int V3   = 100000;
static constexpr int VM   = 25000;
static constexpr int KE   = 128;
static constexpr int E3   = 800000;
static constexpr int EM   = 200000;
static constexpr int C3   = 128;
static constexpr int CMID = 256;

typedef unsigned short u16;
typedef unsigned int   u32;
using short8v = __attribute__((ext_vector_type(8))) short;
using f32x4   = __attribute__((ext_vector_type(4))) float;
using f32x16  = __attribute__((ext_vector_type(16))) float;

#define DEVI __device__ __forceinline__
DEVI float4 ld4(const float* p){ return *(const float4*)p; }
DEVI void   st4(float* p, float4 v){ *(float4*)p = v; }
DEVI float  bf2f(u16 u){ return __uint_as_float(((u32)u) << 16); }
DEVI u16    f2bf(float f){
  u32 u = __float_as_uint(f);
  u += 0x7FFFu + ((u >> 16) & 1u);   // RNE
  return (u16)(u >> 16);
}
DEVI u32 pk2(float a, float b){ return (u32)f2bf(a) | ((u32)f2bf(b) << 16); }
DEVI short8v as8(uint4 v){ union { uint4 u; short8v s; } c; c.u = v; return c.s; }
// swizzled LDS tile addressing (rows of 32 u16 = 4 octets, stride 40 u16)
DEVI int lofs(int row, int oct){ return row * 40 + ((oct ^ ((row >> 3) & 3)) << 3); }

static inline int cdiv(int a, int b){ return (a + b - 1) / b; }

// ---------------- batched-dispatch descriptor structs ----------------
struct PrepT { const float* W[22]; u16* WT[22]; int K[22]; int N[22]; };
struct CvtT  { const float* src[2]; u16* dst[2]; int n[2]; };
struct IniT  { const u16* src[4]; u16* dst[4]; };
struct GDesc {
  const int* idx; const float* val; const u16* Ebf; u16* GE;
  int* rowptr; int* deg; int* rank; int* excl; int* bsum;
  uint2* epack; int E; int V;   // packed (col, val-bits) per edge
};
struct G4 { GDesc d[4]; };

// =====================================================================
// MFMA GEMM (proven structure): BM=64 rows, BN=128 cols, 4 waves.
// =====================================================================
template<bool RELU, bool RES, bool GATHER, bool OBF16>
__global__ __launch_bounds__(256)
void k_mgemm(const void* __restrict__ A0, int aty0, int K0,
             const u16* __restrict__ wt0, int wl0, int wo0,
             const void* __restrict__ A1, int aty1, int K1,
             const u16* __restrict__ wt1, int wl1, int wo1,
             const void* __restrict__ A2, int aty2, int K2,
             const u16* __restrict__ wt2, int wl2, int wo2,
             const int* __restrict__ gidx,
             const float* __restrict__ bias, const float* __restrict__ res,
             void* __restrict__ OUT, u16* __restrict__ OUTB, int CO, int V)
{
  __shared__ __align__(16) u16 As[64 * 40];
  __shared__ __align__(16) u16 Ws[128 * 40];

  const int tid  = threadIdx.x;
  const int wave = tid >> 6, lane = tid & 63;
  const int vbase = blockIdx.x * 64;
  const int ncol0 = blockIdx.y * 128;
  const int KT = K0 + K1 + K2;

  f32x4 acc[8];
  #pragma unroll
  for (int n = 0; n < 8; n++) { acc[n][0]=0.f; acc[n][1]=0.f; acc[n][2]=0.f; acc[n][3]=0.f; }

  const int ar = tid >> 2, ac = tid & 3;
  const int arow = vbase + ar;
  int grow0 = arow;
  if (GATHER && arow < V) grow0 = gidx[arow];

  for (int kt = 0; kt < KT; kt += 32) {
    { // A stage
      int kg = kt + ac * 8;
      uint4 aw = make_uint4(0,0,0,0);
      if (arow < V && kg < KT) {
        const void* src; int aty, koff, sK; bool s0;
        if (kg < K0)            { src=A0; aty=aty0; koff=0;     sK=K0; s0=true;  }
        else if (kg < K0 + K1)  { src=A1; aty=aty1; koff=K0;    sK=K1; s0=false; }
        else                    { src=A2; aty=aty2; koff=K0+K1; sK=K2; s0=false; }
        int row = (GATHER && s0) ? grow0 : arow;
        int kl = kg - koff;
        if (aty) {
          aw = *(const uint4*)((const u16*)src + (size_t)row * sK + kl);
        } else {
          const float* fp = (const float*)src + (size_t)row * sK + kl;
          float4 x = ld4(fp), y = ld4(fp + 4);
          aw = make_uint4(pk2(x.x,x.y), pk2(x.z,x.w), pk2(y.x,y.y), pk2(y.z,y.w));
        }
      }
      *(uint4*)&As[ar * 40 + ac * 8] = aw;
    }
    #pragma unroll
    for (int i = 0; i < 2; i++) { // W stage
      int col = tid & 127;
      int c = (tid >> 7) + 2 * i;
      int kg = kt + c * 8;
      uint4 ww = make_uint4(0,0,0,0);
      if (kg < KT) {
        const u16* wt; int koff, wl, wo;
        if (kg < K0)           { wt=wt0; koff=0;     wl=wl0; wo=wo0; }
        else if (kg < K0+K1)   { wt=wt1; koff=K0;    wl=wl1; wo=wo1; }
        else                   { wt=wt2; koff=K0+K1; wl=wl2; wo=wo2; }
        ww = *(const uint4*)(wt + (size_t)(ncol0 + col) * wl + wo + (kg - koff));
      }
      *(uint4*)&Ws[col * 40 + c * 8] = ww;
    }
    __syncthreads();
    {
      const int mrow = (wave << 4) + (lane & 15);
      const int kc = lane >> 4;
      short8v a = *(const short8v*)(const void*)&As[mrow * 40 + kc * 8];
      #pragma unroll
      for (int n = 0; n < 8; n++) {
        short8v b = *(const short8v*)(const void*)&Ws[(n * 16 + (lane & 15)) * 40 + kc * 8];
        acc[n] = __builtin_amdgcn_mfma_f32_16x16x32_bf16(a, b, acc[n], 0, 0, 0);
      }
    }
    __syncthreads();
  }

  const int q4 = (lane >> 4) * 4, colb = lane & 15;
  #pragma unroll
  for (int n = 0; n < 8; n++) {
    int gcol = ncol0 + n * 16 + colb;
    float bv = bias ? bias[gcol] : 0.f;
    #pragma unroll
    for (int q = 0; q < 4; q++) {
      int grow = vbase + (wave << 4) + q4 + q;
      if (grow >= V) continue;
      float o = acc[n][q] + bv;
      size_t idx = (size_t)grow * CO + gcol;
      if (RES) o += res[idx];
      if (RELU) o = fmaxf(o, 0.f);
      if (OBF16) ((u16*)OUT)[idx] = f2bf(o);
      else {
        ((float*)OUT)[idx] = o;
        if (OUTB) OUTB[idx] = f2bf(o);
      }
    }
  }
}

// =====================================================================
// Fused C3-block MLP (round-7 proven form):
// h1=relu([x|gf|E]@w0+b0); h2=relu(h1@w1+b1); out=h2@w2+b2+XM -> XM,SHB
// =====================================================================
__global__ __launch_bounds__(256)
void k_mlp3(const u16* __restrict__ A0, const u16* __restrict__ A1,
            const u16* __restrict__ A2,                     // [V][128] each
            const u16* __restrict__ w0t,                    // [128][384] x|gf|SW
            const u16* __restrict__ w1t, const u16* __restrict__ w2t, // [128][128]
            const float* __restrict__ b0, const float* __restrict__ b1,
            const float* __restrict__ b2,
            float* __restrict__ XM, u16* __restrict__ SHB, int V)
{
  __shared__ __align__(16) u16 As[64 * 40];
  __shared__ __align__(16) u16 Ws[128 * 40];
  __shared__ __align__(16) u16 Hs[4][64 * 40];

  const int tid  = threadIdx.x;
  const int wave = tid >> 6, lane = tid & 63;
  const int vbase = blockIdx.x * 64;
  const int ar = tid >> 2, ac = tid & 3;
  const int arow = vbase + ar;
  const bool rok = arow < V;
  const int mrow = (wave << 4) + (lane & 15);
  const int kc = lane >> 4;
  const int q4 = (lane >> 4) * 4, colb = lane & 15;

  f32x4 acc[8];
  auto zacc = [&]{
    #pragma unroll
    for (int n = 0; n < 8; n++) { acc[n][0]=0.f; acc[n][1]=0.f; acc[n][2]=0.f; acc[n][3]=0.f; }
  };
  auto hwrite = [&](const float* b){
    #pragma unroll
    for (int n = 0; n < 8; n++) {
      int c = n * 16 + colb;
      float bv = b[c];
      #pragma unroll
      for (int q = 0; q < 4; q++) {
        int row = (wave << 4) + q4 + q;
        Hs[c >> 5][lofs(row, (c >> 3) & 3) + (c & 7)] = f2bf(fmaxf(acc[n][q] + bv, 0.f));
      }
    }
  };
  auto mfma_tile = [&](const u16* a8){
    short8v a = *(const short8v*)(const void*)a8;
    #pragma unroll
    for (int n = 0; n < 8; n++) {
      short8v b = *(const short8v*)(const void*)&Ws[(n * 16 + (lane & 15)) * 40 + kc * 8];
      acc[n] = __builtin_amdgcn_mfma_f32_16x16x32_bf16(a, b, acc[n], 0, 0, 0);
    }
  };

  // ---------- phase 1: KT=384 over [A0|A1|A2], weights w0t ----------
  zacc();
  for (int kt = 0; kt < 384; kt += 32) {
    {
      int kg = kt + ac * 8;
      const u16* src = (kg < 128) ? A0 : (kg < 256) ? A1 : A2;
      int kl = kg & 127;
      uint4 aw = make_uint4(0,0,0,0);
      if (rok) aw = *(const uint4*)(src + (size_t)arow * 128 + kl);
      *(uint4*)&As[ar * 40 + ac * 8] = aw;
    }
    #pragma unroll
    for (int i = 0; i < 2; i++) {
      int col = tid & 127, c = (tid >> 7) + 2 * i;
      *(uint4*)&Ws[col * 40 + c * 8] =
        *(const uint4*)(w0t + (size_t)col * 384 + kt + c * 8);
    }
    __syncthreads();
    mfma_tile(&As[mrow * 40 + kc * 8]);
    __syncthreads();
  }
  hwrite(b0);
  // ---------- phase 2: K=128 over Hs, weights w1t ----------
  zacc();
  for (int kt = 0; kt < 128; kt += 32) {
    #pragma unroll
    for (int i = 0; i < 2; i++) {
      int col = tid & 127, c = (tid >> 7) + 2 * i;
      *(uint4*)&Ws[col * 40 + c * 8] =
        *(const uint4*)(w1t + (size_t)col * 128 + kt + c * 8);
    }
    __syncthreads();   // orders hwrite + Ws stage before reads
    mfma_tile(&Hs[kt >> 5][lofs(mrow, kc)]);
    __syncthreads();
  }
  hwrite(b1);
  // ---------- phase 3: K=128 over Hs, weights w2t + residual epilogue ----------
  zacc();
  for (int kt = 0; kt < 128; kt += 32) {
    #pragma unroll
    for (int i = 0; i < 2; i++) {
      int col = tid & 127, c = (tid >> 7) + 2 * i;
      *(uint4*)&Ws[col * 40 + c * 8] =
        *(const uint4*)(w2t + (size_t)col * 128 + kt + c * 8);
    }
    __syncthreads();
    mfma_tile(&Hs[kt >> 5][lofs(mrow, kc)]);
    __syncthreads();
  }
  #pragma unroll
  for (int n = 0; n < 8; n++) {
    int gcol = n * 16 + colb;
    float bv = b2[gcol];
    #pragma unroll
    for (int q = 0; q < 4; q++) {
      int grow = vbase + (wave << 4) + q4 + q;
      if (grow >= V) continue;
      size_t idx = (size_t)grow * C3 + gcol;
      float o = acc[n][q] + bv + XM[idx];
      XM[idx] = o;
      SHB[idx] = f2bf(o);
    }
  }
}

// =====================================================================
// Register-resident MFMA megagate (no LDS, no barriers).
// =====================================================================
__global__ __launch_bounds__(256)
void k_mgate_reg(const u16* __restrict__ GEX, const u16* __restrict__ GEY,
                 const u16* __restrict__ pS, const u16* __restrict__ pR,
                 const u16* __restrict__ pI,
                 u16* __restrict__ GF, int CO, int V)
{
  const int lane = threadIdx.x & 63;
  const int wave = threadIdx.x >> 6;
  const int rbase = blockIdx.x * 128 + wave * 32;
  const int arow = rbase + (lane & 31);
  const int koff = (lane >> 5) * 8;
  const bool rok = arow < V;

  uint4 ax[8], ay[8], an[8];
  #pragma unroll
  for (int kt = 0; kt < 8; kt++) {
    uint4 zx = make_uint4(0,0,0,0), zy = make_uint4(0,0,0,0);
    if (rok) {
      zx = *(const uint4*)(GEX + (size_t)arow * KE + kt * 16 + koff);
      zy = *(const uint4*)(GEY + (size_t)arow * KE + kt * 16 + koff);
    }
    ax[kt] = zx; ay[kt] = zy;
    an[kt] = make_uint4(zy.x ^ 0x80008000u, zy.y ^ 0x80008000u,
                        zy.z ^ 0x80008000u, zy.w ^ 0x80008000u);
  }

  const int ngr = CO >> 5;
  for (int g = 0; g < ngr; g++) {
    f32x16 gx, gy, br, bi;
    #pragma unroll
    for (int r = 0; r < 16; r++) { gx[r]=0.f; gy[r]=0.f; br[r]=0.f; bi[r]=0.f; }
    #pragma unroll
    for (int kt = 0; kt < 8; kt++) {
      size_t bo = ((size_t)(g * 8 + kt) * 64 + lane) * 8;
      short8v bs  = *(const short8v*)(const void*)(pS + bo);
      short8v brv = *(const short8v*)(const void*)(pR + bo);
      short8v biv = *(const short8v*)(const void*)(pI + bo);
      short8v axv = as8(ax[kt]), ayv = as8(ay[kt]), anv = as8(an[kt]);
      gx = __builtin_amdgcn_mfma_f32_32x32x16_bf16(axv, bs,  gx, 0, 0, 0);
      gy = __builtin_amdgcn_mfma_f32_32x32x16_bf16(ayv, bs,  gy, 0, 0, 0);
      br = __builtin_amdgcn_mfma_f32_32x32x16_bf16(axv, brv, br, 0, 0, 0);
      br = __builtin_amdgcn_mfma_f32_32x32x16_bf16(anv, biv, br, 0, 0, 0);
      bi = __builtin_amdgcn_mfma_f32_32x32x16_bf16(axv, biv, bi, 0, 0, 0);
      bi = __builtin_amdgcn_mfma_f32_32x32x16_bf16(ayv, brv, bi, 0, 0, 0);
    }
    const int col = g * 32 + (lane & 31);
    const int rhi = 4 * (lane >> 5);
    #pragma unroll
    for (int r = 0; r < 16; r++) {
      int row = rbase + (r & 3) + 8 * (r >> 2) + rhi;
      if (row < V) {
        float o = tanhf(gx[r] * br[r] + gy[r] * bi[r]);
        GF[(size_t)row * CO + col] = f2bf(o);
      }
    }
  }
}

// =====================================================================
// MFMA spectral down-projection (bf16 inputs), split-K + f32 atomics.
// =====================================================================
__global__ __launch_bounds__(256)
void k_specmm(const u16* __restrict__ E, const u16* __restrict__ X,
              const float* __restrict__ mass, float* __restrict__ SPEC,
              int C, int V, int CH)
{
  __shared__ __align__(16) u16 As[64 * 40];
  __shared__ __align__(16) u16 Bs[128 * 40];

  const int tid = threadIdx.x;
  const int wave = tid >> 6, lane = tid & 63;
  const int m0 = blockIdx.y * 64;
  const int n0 = blockIdx.z * 128;
  const int vs = blockIdx.x * CH;
  const int ve = min(V, vs + CH);

  f32x4 acc[8];
  #pragma unroll
  for (int n = 0; n < 8; n++) { acc[n][0]=0.f; acc[n][1]=0.f; acc[n][2]=0.f; acc[n][3]=0.f; }

  const int am = tid & 63, ac = tid >> 6;
  const int bcol = tid & 127, bc0 = (tid >> 7) * 2;

  u16 ea[8]; float fb0[8], fb1[8], fm0[8], fm1[8];
  auto loadA = [&](int kt) {
    #pragma unroll
    for (int j = 0; j < 8; j++) {
      int v = kt + ac * 8 + j;
      ea[j] = (v < ve) ? E[(size_t)v * KE + m0 + am] : (u16)0;
    }
  };
  auto loadB = [&](int kt) {
    #pragma unroll
    for (int j = 0; j < 8; j++) {
      int v0 = kt + bc0 * 8 + j, v1 = v0 + 8;
      fb0[j] = (v0 < ve) ? bf2f(X[(size_t)v0 * C + n0 + bcol]) : 0.f;
      fm0[j] = (v0 < ve) ? mass[v0] : 0.f;
      fb1[j] = (v1 < ve) ? bf2f(X[(size_t)v1 * C + n0 + bcol]) : 0.f;
      fm1[j] = (v1 < ve) ? mass[v1] : 0.f;
    }
  };
  loadA(vs); loadB(vs);

  for (int kt = vs; kt < ve; kt += 32) {
    __syncthreads();
    *(uint4*)&As[lofs(am, ac)] = make_uint4(
        (u32)ea[0] | ((u32)ea[1] << 16), (u32)ea[2] | ((u32)ea[3] << 16),
        (u32)ea[4] | ((u32)ea[5] << 16), (u32)ea[6] | ((u32)ea[7] << 16));
    float t0[8], t1[8];
    #pragma unroll
    for (int j = 0; j < 8; j++) { t0[j] = fb0[j]*fm0[j]; t1[j] = fb1[j]*fm1[j]; }
    *(uint4*)&Bs[lofs(bcol, bc0)] = make_uint4(
        pk2(t0[0],t0[1]), pk2(t0[2],t0[3]), pk2(t0[4],t0[5]), pk2(t0[6],t0[7]));
    *(uint4*)&Bs[lofs(bcol, bc0 + 1)] = make_uint4(
        pk2(t1[0],t1[1]), pk2(t1[2],t1[3]), pk2(t1[4],t1[5]), pk2(t1[6],t1[7]));
    __syncthreads();
    if (kt + 32 < ve) { loadA(kt + 32); loadB(kt + 32); }
    const int kc = lane >> 4, ml = lane & 15;
    short8v a = *(const short8v*)(const void*)&As[lofs(wave * 16 + ml, kc)];
    #pragma unroll
    for (int n = 0; n < 8; n++) {
      short8v b = *(const short8v*)(const void*)&Bs[lofs(n * 16 + ml, kc)];
      acc[n] = __builtin_amdgcn_mfma_f32_16x16x32_bf16(a, b, acc[n], 0, 0, 0);
    }
  }

  const int q4 = (lane >> 4) * 4, colb = lane & 15;
  #pragma unroll
  for (int n = 0; n < 8; n++) {
    int col = n0 + n * 16 + colb;
    #pragma unroll
    for (int q = 0; q < 4; q++) {
      int row = m0 + wave * 16 + q4 + q;
      unsafeAtomicAdd(&SPEC[(size_t)row * C + col], acc[n][q]);
    }
  }
}

// =====================================================================
// smallprep: packed B-fragment S/Tr/Ti + flat SWt; zeroes SPEC after
// reading. If wcmb != null also writes SW into wCmb slot.
// =====================================================================
template<int C>
__global__ void k_smallprep(float* __restrict__ SPEC, const float* __restrict__ evals,
                            const float* __restrict__ dt, const float* __restrict__ Are,
                            const float* __restrict__ Aim, const float* __restrict__ w0,
                            u16* __restrict__ pS, u16* __restrict__ pR,
                            u16* __restrict__ pI, u16* __restrict__ SWt,
                            u16* __restrict__ wcmb)
{
  __shared__ float sld[C];
  const int k = blockIdx.x;
  const int c = threadIdx.x;
  const float ev = evals[k];
  float s = expf(-ev * fmaxf(dt[c], 1e-8f)) * SPEC[(size_t)k * C + c];
  SPEC[(size_t)k * C + c] = 0.f;   // re-zero for the next block's atomics
  sld[c] = s;
  const size_t pidx = ((size_t)((c >> 5) * 8 + (k >> 4)) * 64
                       + (c & 31) + ((k >> 3) & 1) * 32) * 8 + (k & 7);
  pS[pidx] = f2bf(s);
  __syncthreads();
  float tr = 0.f, ti = 0.f, sw = 0.f;
  for (int j = 0; j < C; j++) {
    float sj = sld[j];
    tr = fmaf(sj, Are[(size_t)j * C + c], tr);
    ti = fmaf(sj, Aim[(size_t)j * C + c], ti);
    sw = fmaf(sj, w0[(size_t)(C + j) * C + c], sw);
  }
  pR[pidx] = f2bf(tr);
  pI[pidx] = f2bf(ti);
  u16 swb = f2bf(sw);
  SWt[(size_t)c * 128 + k] = swb;
  if (wcmb) wcmb[(size_t)c * 384 + 256 + k] = swb;
}

// ===== batched weight pre-transpose: 22 entries, grid (768, 22) =====
__global__ void k_prepw_b(PrepT p) {
  int e = blockIdx.y;
  int i = blockIdx.x * 256 + threadIdx.x;
  int K = p.K[e], N = p.N[e];
  if (i < K * N) {
    int k = i / N, n = i % N;
    p.WT[e][(size_t)n * K + k] = f2bf(p.W[e][i]);
  }
}

// ===== batched f32->bf16 cvt: 2 entries =====
__global__ void k_cvt_b(CvtT c) {
  int e = blockIdx.y;
  int i = (blockIdx.x * 256 + threadIdx.x) * 4;
  if (i < c.n[e]) {
    float4 v = ld4(c.src[e] + i);
    ushort4 o; o.x = f2bf(v.x); o.y = f2bf(v.y); o.z = f2bf(v.z); o.w = f2bf(v.w);
    *(ushort4*)(c.dst[e] + i) = o;
  }
}

// ===== init 4 wCmb static parts: [col][0:128]=x, [128:256]=gf =====
__global__ void k_initwc(IniT t) {
  int e = blockIdx.y;
  int i = blockIdx.x * 256 + threadIdx.x;   // 32768 elements
  int col = i >> 8, k = i & 255;
  t.dst[e][(size_t)col * 384 + k] =
      (k < 128) ? t.src[e][(size_t)col * 384 + k]
                : t.src[e][(size_t)col * 384 + 128 + k];
}

// ===== f32 -> bf16 single (decoder rebuild) =====
__global__ void k_cvt(const float* __restrict__ in, u16* __restrict__ out, int n) {
  int i = (blockIdx.x * 256 + threadIdx.x) * 4;
  if (i < n) {
    float4 v = ld4(in + i);
    ushort4 o; o.x = f2bf(v.x); o.y = f2bf(v.y); o.z = f2bf(v.z); o.w = f2bf(v.w);
    *(ushort4*)(out + i) = o;
  }
}

// ==================== batched 4-graph CSR build ======================
// hist ALSO captures each edge's within-row rank (the atomic's return
// value) so the scatter pass needs NO atomic at all.
__global__ void k_bhist(G4 g) {
  const GDesc& d = g.d[blockIdx.y];
  int e = blockIdx.x * 256 + threadIdx.x;
  if (e < d.E) d.rank[e] = atomicAdd(&d.deg[d.idx[2 * e]], 1);
}
__global__ void k_bscan1(G4 g) {
  const GDesc& d = g.d[blockIdx.y];
  __shared__ int sd[256];
  int t = threadIdx.x;
  int i = blockIdx.x * 256 + t;
  int v = (i < d.V) ? d.deg[i] : 0;
  sd[t] = v;
  __syncthreads();
  for (int off = 1; off < 256; off <<= 1) {
    int add = (t >= off) ? sd[t - off] : 0;
    __syncthreads();
    sd[t] += add;
    __syncthreads();
  }
  if (i < d.V) d.excl[i] = sd[t] - v;
  if (t == 255) d.bsum[blockIdx.x] = sd[255];
}
__global__ void k_bscan2(G4 g, int nb) {
  const GDesc& d = g.d[blockIdx.y];
  __shared__ int sd[512];
  int t = threadIdx.x;
  int v = (t < nb) ? d.bsum[t] : 0;
  sd[t] = v;
  __syncthreads();
  for (int off = 1; off < 512; off <<= 1) {
    int add = (t >= off) ? sd[t - off] : 0;
    __syncthreads();
    sd[t] += add;
    __syncthreads();
  }
  if (t < nb) d.bsum[t] = sd[t] - v;
  if (t == 0) d.rowptr[d.V] = sd[511];
}
__global__ void k_bscan3(G4 g) {
  const GDesc& d = g.d[blockIdx.y];
  int i = blockIdx.x * 256 + threadIdx.x;
  if (i < d.V) d.rowptr[i] = d.excl[i] + d.bsum[i >> 8];
}
// atomic-free packed scatter: ONE 8B store per edge.
__global__ void k_bscatter(G4 g) {
  const GDesc& d = g.d[blockIdx.y];
  int e = blockIdx.x * 256 + threadIdx.x;
  if (e < d.E) {
    int dd = d.idx[2 * e];
    int p = d.rowptr[dd] + d.rank[e];
    d.epack[p] = make_uint2((u32)d.idx[2 * e + 1], __float_as_uint(d.val[e]));
  }
}
// 4-way edge-unrolled gather spmm over packed edges (4 gathers in flight).
__global__ __launch_bounds__(256)
void k_bspmm(G4 g) {
  const GDesc& d = g.d[blockIdx.y];
  int r = blockIdx.x * 8 + (threadIdx.x >> 5);
  int lane = threadIdx.x & 31;
  if (r >= d.V) return;
  int j0 = d.rowptr[r], j1 = d.rowptr[r + 1];
  float4 a0 = make_float4(0.f,0.f,0.f,0.f);
  float4 a1 = make_float4(0.f,0.f,0.f,0.f);
  float4 a2 = make_float4(0.f,0.f,0.f,0.f);
  float4 a3 = make_float4(0.f,0.f,0.f,0.f);
  int j = j0;
  for (; j + 4 <= j1; j += 4) {
    uint2 e0 = d.epack[j],     e1 = d.epack[j + 1];
    uint2 e2 = d.epack[j + 2], e3 = d.epack[j + 3];
    float v0 = __uint_as_float(e0.y), v1 = __uint_as_float(e1.y);
    float v2 = __uint_as_float(e2.y), v3 = __uint_as_float(e3.y);
    ushort4 x0 = *(const ushort4*)(d.Ebf + (size_t)e0.x * KE + lane * 4);
    ushort4 x1 = *(const ushort4*)(d.Ebf + (size_t)e1.x * KE + lane * 4);
    ushort4 x2 = *(const ushort4*)(d.Ebf + (size_t)e2.x * KE + lane * 4);
    ushort4 x3 = *(const ushort4*)(d.Ebf + (size_t)e3.x * KE + lane * 4);
    a0.x = fmaf(v0, bf2f(x0.x), a0.x); a0.y = fmaf(v0, bf2f(x0.y), a0.y);
    a0.z = fmaf(v0, bf2f(x0.z), a0.z); a0.w = fmaf(v0, bf2f(x0.w), a0.w);
    a1.x = fmaf(v1, bf2f(x1.x), a1.x); a1.y = fmaf(v1, bf2f(x1.y), a1.y);
    a1.z = fmaf(v1, bf2f(x1.z), a1.z); a1.w = fmaf(v1, bf2f(x1.w), a1.w);
    a2.x = fmaf(v2, bf2f(x2.x), a2.x); a2.y = fmaf(v2, bf2f(x2.y), a2.y);
    a2.z = fmaf(v2, bf2f(x2.z), a2.z); a2.w = fmaf(v2, bf2f(x2.w), a2.w);
    a3.x = fmaf(v3, bf2f(x3.x), a3.x); a3.y = fmaf(v3, bf2f(x3.y), a3.y);
    a3.z = fmaf(v3, bf2f(x3.z), a3.z); a3.w = fmaf(v3, bf2f(x3.w), a3.w);
  }
  if (j + 2 <= j1) {
    uint2 e0 = d.epack[j], e1 = d.epack[j + 1];
    float v0 = __uint_as_float(e0.y), v1 = __uint_as_float(e1.y);
    ushort4 x0 = *(const ushort4*)(d.Ebf + (size_t)e0.x * KE + lane * 4);
    ushort4 x1 = *(const ushort4*)(d.Ebf + (size_t)e1.x * KE + lane * 4);
    a0.x = fmaf(v0, bf2f(x0.x), a0.x); a0.y = fmaf(v0, bf2f(x0.y), a0.y);
    a0.z = fmaf(v0, bf2f(x0.z), a0.z); a0.w = fmaf(v0, bf2f(x0.w), a0.w);
    a1.x = fmaf(v1, bf2f(x1.x), a1.x); a1.y = fmaf(v1, bf2f(x1.y), a1.y);
    a1.z = fmaf(v1, bf2f(x1.z), a1.z); a1.w = fmaf(v1, bf2f(x1.w), a1.w);
    j += 2;
  }
  if (j < j1) {
    uint2 e0 = d.epack[j];
    float v0 = __uint_as_float(e0.y);
    ushort4 x0 = *(const ushort4*)(d.Ebf + (size_t)e0.x * KE + lane * 4);
    a0.x = fmaf(v0, bf2f(x0.x), a0.x); a0.y = fmaf(v0, bf2f(x0.y), a0.y);
    a0.z = fmaf(v0, bf2f(x0.z), a0.z); a0.w = fmaf(v0, bf2f(x0.w), a0.w);
  }
  a0.x += a1.x + a2.x + a3.x;
  a0.y += a1.y + a2.y + a3.y;
  a0.z += a1.z + a2.z + a3.z;
  a0.w += a1.w + a2.w + a3.w;
  ushort4 o;
  o.x = f2bf(a0.x); o.y = f2bf(a0.y); o.z = f2bf(a0.z); o.w = f2bf(a0.w);
  *(ushort4*)(d.GE + (size_t)r * KE + lane * 4) = o;
}

// ============================ segment max ============================
__global__ void k_segmax_init(unsigned* __restrict__ u, int n) {
  int i = blockIdx.x * 256 + threadIdx.x;
  if (i < n) u[i] = 0x007FFFFFu;
}
__global__ void k_segmax_scatter(const u16* __restrict__ X, const int* __restrict__ tr,
                                 unsigned* __restrict__ u) {
  int i = blockIdx.x * 256 + threadIdx.x;
  if (i >= V3 * C3) return;
  int v = i >> 7, c = i & 127;
  unsigned b = ((unsigned)X[i]) << 16;
  unsigned m = (b & 0x80000000u) ? ~b : (b | 0x80000000u);
  atomicMax(&u[((size_t)tr[v] << 7) + c], m);
}
__global__ void k_segmax_decode(const unsigned* __restrict__ u, u16* __restrict__ out, int n) {
  int i = blockIdx.x * 256 + threadIdx.x;
  if (i < n) {
    unsigned m = u[i];
    unsigned b = 0;
    if (m != 0x007FFFFFu)
      b = (m & 0x80000000u) ? (m & 0x7FFFFFFFu) : ~m;
    out[i] = (u16)(b >> 16);
  }
}

// ========================= final projection ==========================
__global__ __launch_bounds__(256)
void k_outproj(const float* __restrict__ Y, const float* __restrict__ W,
               const float* __restrict__ B, float* __restrict__ OUT, int V) {
  __shared__ float Wl[128][22];
  __shared__ float ys[8][128];
  const int tid = threadIdx.x;
  for (int f = tid; f < 128 * 21; f += 256) Wl[f / 21][f % 21] = W[f];
  {
    int r = tid >> 5, cc = (tid & 31) * 4;
    int v = blockIdx.x * 8 + r;
    float4 yv = make_float4(0.f,0.f,0.f,0.f);
    if (v < V) yv = ld4(Y + (size_t)v * C3 + cc);
    st4(&ys[r][cc], yv);
  }
  __syncthreads();
  int r = tid >> 5, c = tid & 31;
  int v = blockIdx.x * 8 + r;
  if (v < V && c < 21) {
    float acc = B[c];
    #pragma unroll 8
    for (int k = 0; k < 128; k++) acc = fmaf(ys[r][k], Wl[k][c], acc);
    OUT[(size_t)v * 21 + c] = acc;
  }
}

// =====================================================================
extern "C" void kernel_launch(void* const* d_in, const int* in_sizes, int n_in,
                              void* d_out, int out_size, void* d_ws, size_t ws_size,
                              hipStream_t stream)
{
  (void)in_sizes; (void)n_in; (void)out_size;
  const float* x_in    = (const float*)d_in[0];
  const float* mass3   = (const float*)d_in[1];
  const float* evals3  = (const float*)d_in[2];
  const float* evecs3  = (const float*)d_in[3];
  const int*   gX3i    = (const int*)d_in[4];
  const float* gX3v    = (const float*)d_in[5];
  const int*   gY3i    = (const int*)d_in[6];
  const float* gY3v    = (const float*)d_in[7];
  const float* massm   = (const float*)d_in[8];
  const float* evalsm  = (const float*)d_in[9];
  const float* evecsm  = (const float*)d_in[10];
  const int*   gXmi    = (const int*)d_in[11];
  const float* gXmv    = (const float*)d_in[12];
  const int*   gYmi    = (const int*)d_in[13];
  const float* gYmv    = (const float*)d_in[14];
  const int*   tr34    = (const int*)d_in[15];
  const float* in_w    = (const float*)d_in[16];
  const float* in_b    = (const float*)d_in[17];
  const float* widen_w = (const float*)d_in[18];
  const float* widen_b = (const float*)d_in[19];
  const float* narrow_w= (const float*)d_in[20];
  const float* narrow_b= (const float*)d_in[21];
  const float* halve_w = (const float*)d_in[22];
  const float* halve_b = (const float*)d_in[23];
  const float* out_w   = (const float*)d_in[24];
  const float* out_b   = (const float*)d_in[25];
  const float* enc_p[9]; const float* mid_p[9]; const float* dec_p[9];
  for (int i = 0; i < 9; i++) {
    enc_p[i] = (const float*)d_in[26 + i];
    mid_p[i] = (const float*)d_in[35 + i];
    dec_p[i] = (const float*)d_in[44 + i];
  }

  // ---------------- workspace layout (~214 MB) ----------------
  char* ws = (char*)d_ws;
  size_t off = 0;
  float* XM  = (float*)(ws + off); off += (size_t)V3 * C3 * 4;
  u16* SHB   = (u16*)(ws + off);   off += (size_t)V3 * C3 * 2;
  u16* GEX3  = (u16*)(ws + off);   off += (size_t)V3 * KE * 2;
  u16* GEY3  = (u16*)(ws + off);   off += (size_t)V3 * KE * 2;
  u16* GEXm  = (u16*)(ws + off);   off += (size_t)VM * KE * 2;
  u16* GEYm  = (u16*)(ws + off);   off += (size_t)VM * KE * 2;
  u16* BSCR  = (u16*)(ws + off);   off += (size_t)V3 * C3 * 2;
  char* E3R  = (char*)(ws + off);  off += (size_t)V3 * KE * 2;
  u16* Embf  = (u16*)(ws + off);   off += (size_t)VM * KE * 2;
  u16* SHM   = (u16*)(ws + off);   off += (size_t)VM * CMID * 2;
  float* spec= (float*)(ws + off); off += 131072;
  u16* pS  = (u16*)(ws + off); off += 65536;
  u16* pR  = (u16*)(ws + off); off += 65536;
  u16* pI  = (u16*)(ws + off); off += 65536;
  u16* SWt = (u16*)(ws + off); off += 65536;
  u16* wT  = (u16*)(ws + off); off += 2800000;
  const size_t NEED = off;
  if (ws_size < NEED) return;

  u16*   E3bf = (u16*)E3R;
  float* M0   = (float*)E3R;
  // pool overlays BSCR (dead at pool time)
  unsigned* xm_u  = (unsigned*)BSCR;
  u16*      xm_dec= (u16*)((char*)BSCR + 12800000);
  u16* BSCR0 = BSCR;
  u16* BSCR1 = BSCR + (size_t)VM * CMID;

  u16* in_wt    = wT + 0;
  u16* widen_t  = wT + 2048;
  u16* narrow_t = wT + 34816;
  u16* halve_t  = wT + 67584;
  u16* enc_w0t  = wT + 100352;
  u16* enc_w1t  = wT + 198656;
  u16* enc_w2t  = wT + 231424;
  u16* mid_w0t  = wT + 264192;
  u16* mid_w1t  = wT + 657408;
  u16* mid_w2t  = wT + 788480;
  u16* dec_w0t  = wT + 919552;
  u16* dec_w1t  = wT + 1017856;
  u16* dec_w2t  = wT + 1050624;
  u16* wCmb[4]  = { wT + 1083392, wT + 1181696, wT + 1280000, wT + 1378304 };

  // ---- batched weight pre-transpose (1 dispatch) ----
  {
    PrepT p;
    int e = 0;
    auto add = [&](const float* W, u16* WT, int K, int N, int z) {
      for (int i = 0; i < z; i++) {
        p.W[e] = W + (size_t)i * K * N; p.WT[e] = WT + (size_t)i * K * N;
        p.K[e] = K; p.N[e] = N; e++;
      }
    };
    add(in_w, in_wt, 16, 128, 1);
    add(widen_w, widen_t, 128, 256, 1);
    add(narrow_w, narrow_t, 256, 128, 1);
    add(halve_w, halve_t, 256, 128, 1);
    add(enc_p[3], enc_w0t, 384, 128, 2);
    add(enc_p[5], enc_w1t, 128, 128, 2);
    add(enc_p[7], enc_w2t, 128, 128, 2);
    add(mid_p[3], mid_w0t, 768, 256, 2);
    add(mid_p[5], mid_w1t, 256, 256, 2);
    add(mid_p[7], mid_w2t, 256, 256, 2);
    add(dec_p[3], dec_w0t, 384, 128, 2);
    add(dec_p[5], dec_w1t, 128, 128, 2);
    add(dec_p[7], dec_w2t, 128, 128, 2);
    k_prepw_b<<<dim3(768, 22), 256, 0, stream>>>(p);
  }
  // ---- init static parts of the 4 combined-w0 buffers (1 dispatch) ----
  {
    IniT t;
    t.src[0] = enc_w0t; t.dst[0] = wCmb[0];
    t.src[1] = enc_w0t + 49152; t.dst[1] = wCmb[1];
    t.src[2] = dec_w0t; t.dst[2] = wCmb[2];
    t.src[3] = dec_w0t + 49152; t.dst[3] = wCmb[3];
    k_initwc<<<dim3(128, 4), 256, 0, stream>>>(t);
  }
  // ---- evecs -> bf16 (1 dispatch) ----
  {
    CvtT c;
    c.src[0] = evecs3; c.dst[0] = E3bf; c.n[0] = V3 * KE;
    c.src[1] = evecsm; c.dst[1] = Embf; c.n[1] = VM * KE;
    k_cvt_b<<<dim3(cdiv(V3 * KE / 4, 256), 2), 256, 0, stream>>>(c);
  }
  // ---- zero spec ONCE (smallprep re-zeros after each read) ----
  hipMemsetAsync(spec, 0, (size_t)KE * CMID * 4, stream);

  // ---- batched 4-graph CSR build + spmm (7 dispatches) ----
  {
    int* degs = (int*)BSCR;          // 250000 ints
    int* pos  = degs + 250000;
    // rank arrays live in GEX3 (dead until bspmm writes it, which is
    // strictly after bscatter consumes rank)
    int* rankbase = (int*)GEX3;      // 2E3+2EM ints = 8 MB <= 25.6 MB
    G4 g;
    const int*   idxs[4] = { gX3i, gY3i, gXmi, gYmi };
    const float* vals[4] = { gX3v, gY3v, gXmv, gYmv };
    const u16*   ebfs[4] = { E3bf, E3bf, Embf, Embf };
    u16*         ges[4]  = { GEX3, GEY3, GEXm, GEYm };
    int Es[4] = { E3, E3, EM, EM };
    int Vs[4] = { V3, V3, VM, VM };
    int doff[4] = { 0, 100000, 200000, 225000 };
    int roff[4] = { 0, E3, 2 * E3, 2 * E3 + EM };
    for (int i = 0; i < 4; i++) {
      GDesc& d = g.d[i];
      d.idx = idxs[i]; d.val = vals[i]; d.Ebf = ebfs[i]; d.GE = ges[i];
      d.E = Es[i]; d.V = Vs[i];
      d.deg = degs + doff[i];
      d.rank = rankbase + roff[i];
      d.rowptr = pos; pos += Vs[i] + 1;
      d.excl   = pos; pos += Vs[i];
      d.bsum   = pos; pos += 512;
      if (((uintptr_t)pos) & 7) pos++;          // 8B-align packed edges
      d.epack  = (uint2*)pos; pos += 2 * Es[i];
    }
    hipMemsetAsync(degs, 0, 250000 * 4, stream);
    k_bhist<<<dim3(cdiv(E3, 256), 4), 256, 0, stream>>>(g);
    k_bscan1<<<dim3(cdiv(V3, 256), 4), 256, 0, stream>>>(g);
    k_bscan2<<<dim3(1, 4), 512, 0, stream>>>(g, cdiv(V3, 256));
    k_bscan3<<<dim3(cdiv(V3, 256), 4), 256, 0, stream>>>(g);
    k_bscatter<<<dim3(cdiv(E3, 256), 4), 256, 0, stream>>>(g);
    k_bspmm<<<dim3(cdiv(V3, 8), 4), 256, 0, stream>>>(g);
  }

  const int G3 = cdiv(V3, 64);   // 1563
  const int GM = cdiv(VM, 64);   // 391

  // ---- block3: 4 dispatches per block (no memset) ----
  auto launch_block3 = [&](const float* p[9],
                           const u16* w1t, const u16* w2t, u16* wc, int i) {
    const float* dt  = p[0] + (size_t)i * C3;
    const float* Are = p[1] + (size_t)i * C3 * C3;
    const float* Aim = p[2] + (size_t)i * C3 * C3;
    const float* w0  = p[3] + (size_t)i * 3 * C3 * C3;
    const float* b0  = p[4] + (size_t)i * C3;
    const float* b1  = p[6] + (size_t)i * C3;
    const float* b2  = p[8] + (size_t)i * C3;
    const u16* w1ti = w1t + (size_t)i * C3 * C3;
    const u16* w2ti = w2t + (size_t)i * C3 * C3;
    k_specmm<<<dim3(cdiv(V3, 256), 2, 1), 256, 0, stream>>>(E3bf, SHB, mass3, spec, C3, V3, 256);
    k_smallprep<C3><<<KE, C3, 0, stream>>>(spec, evals3, dt, Are, Aim, w0, pS, pR, pI, SWt, wc);
    k_mgate_reg<<<cdiv(V3, 128), 256, 0, stream>>>(GEX3, GEY3, pS, pR, pI, BSCR, C3, V3);
    k_mlp3<<<G3, 256, 0, stream>>>(SHB, BSCR, E3bf, wc, w1ti, w2ti,
                                   b0, b1, b2, XM, SHB, V3);
  };

  // ---- blockm: split (proven), no memset ----
  auto run_blockm = [&](const float* p[9],
                        const u16* w0t, const u16* w1t, const u16* w2t, int i) {
    const float* dt  = p[0] + (size_t)i * CMID;
    const float* Are = p[1] + (size_t)i * CMID * CMID;
    const float* Aim = p[2] + (size_t)i * CMID * CMID;
    const float* w0  = p[3] + (size_t)i * 3 * CMID * CMID;
    const float* b0  = p[4] + (size_t)i * CMID;
    const float* b1  = p[6] + (size_t)i * CMID;
    const float* b2  = p[8] + (size_t)i * CMID;
    const u16* w0ti = w0t + (size_t)i * 3 * CMID * CMID;
    const u16* w1ti = w1t + (size_t)i * CMID * CMID;
    const u16* w2ti = w2t + (size_t)i * CMID * CMID;
    k_specmm<<<dim3(cdiv(VM, 128), 2, 2), 256, 0, stream>>>(Embf, SHM, massm, spec, CMID, VM, 128);
    k_smallprep<CMID><<<KE, CMID, 0, stream>>>(spec, evalsm, dt, Are, Aim, w0, pS, pR, pI, SWt, nullptr);
    k_mgate_reg<<<cdiv(VM, 128), 256, 0, stream>>>(GEXm, GEYm, pS, pR, pI, BSCR0, CMID, VM);
    k_mgemm<true,false,false,true><<<dim3(GM, 2), 256, 0, stream>>>(
        SHM, 1, CMID, w0ti, 3*CMID, 0,
        BSCR0, 1, CMID, w0ti, 3*CMID, 2*CMID,
        Embf, 1, KE, SWt, 128, 0,
        nullptr, b0, nullptr, BSCR1, nullptr, CMID, VM);
    k_mgemm<true,false,false,true><<<dim3(GM, 2), 256, 0, stream>>>(
        BSCR1, 1, CMID, w1ti, CMID, 0,
        nullptr,0,0,nullptr,0,0, nullptr,0,0,nullptr,0,0,
        nullptr, b1, nullptr, BSCR0, nullptr, CMID, VM);
    k_mgemm<false,true,false,false><<<dim3(GM, 2), 256, 0, stream>>>(
        BSCR0, 1, CMID, w2ti, CMID, 0,
        nullptr,0,0,nullptr,0,0, nullptr,0,0,nullptr,0,0,
        nullptr, b2, M0, M0, SHM, CMID, VM);
  };

  // ---- encoder ----
  k_mgemm<true,false,false,false><<<dim3(G3, 1), 256, 0, stream>>>(
      x_in, 0, 16, in_wt, 16, 0,
      nullptr,0,0,nullptr,0,0, nullptr,0,0,nullptr,0,0,
      nullptr, in_b, nullptr, XM, SHB, C3, V3);
  launch_block3(enc_p, enc_w1t, enc_w2t, wCmb[0], 0);
  launch_block3(enc_p, enc_w1t, enc_w2t, wCmb[1], 1);        // x3 = XM/SHB

  // ---- pool (reads bf16 shadow; identical by monotonicity) ----
  k_segmax_init<<<cdiv(VM * C3, 256), 256, 0, stream>>>(xm_u, VM * C3);
  k_segmax_scatter<<<cdiv(V3 * C3, 256), 256, 0, stream>>>(SHB, tr34, xm_u);
  k_segmax_decode<<<cdiv(VM * C3, 256), 256, 0, stream>>>(xm_u, xm_dec, VM * C3);
  k_mgemm<true,false,false,false><<<dim3(GM, 2), 256, 0, stream>>>(
      xm_dec, 1, C3, widen_t, C3, 0,
      nullptr,0,0,nullptr,0,0, nullptr,0,0,nullptr,0,0,
      nullptr, widen_b, nullptr, M0, SHM, CMID, VM);
  run_blockm(mid_p, mid_w0t, mid_w1t, mid_w2t, 0);
  run_blockm(mid_p, mid_w0t, mid_w1t, mid_w2t, 1);           // shadow = SHM

  // ---- unpool ----
  k_mgemm<true,false,true,true><<<dim3(G3, 1), 256, 0, stream>>>(
      SHM, 1, CMID, narrow_t, CMID, 0,
      nullptr,0,0,nullptr,0,0, nullptr,0,0,nullptr,0,0,
      tr34, narrow_b, nullptr, BSCR, nullptr, C3, V3);
  k_mgemm<true,false,false,false><<<dim3(G3, 1), 256, 0, stream>>>(
      BSCR, 1, C3, halve_t, 2*C3, 0,
      SHB, 1, C3, halve_t, 2*C3, C3,
      nullptr,0,0,nullptr,0,0,
      nullptr, halve_b, nullptr, XM, SHB, C3, V3);

  // ---- decoder (rebuild E3bf: clobbered by M0 overlay) ----
  k_cvt<<<cdiv(V3 * KE / 4, 256), 256, 0, stream>>>(evecs3, E3bf, V3 * KE);
  launch_block3(dec_p, dec_w1t, dec_w2t, wCmb[2], 0);
  launch_block3(dec_p, dec_w1t, dec_w2t, wCmb[3], 1);

  // ---- output projection ----
  k_outproj<<<cdiv(V3, 8), 256, 0, stream>>>(XM, out_w, out_b, (float*)d_out, V3);
}